// Round 4
// baseline (279.370 us; speedup 1.0000x reference)
//
#include <hip/hip_runtime.h>

#define HW 4096
#define CC 128

typedef unsigned short ushort_t;
typedef unsigned int uint_t;
typedef __attribute__((ext_vector_type(8))) short short8;
typedef __attribute__((ext_vector_type(4))) float f32x4;

__device__ __forceinline__ float dot4(float4 a, float4 b) {
    return (a.x*b.x + a.y*b.y) + (a.z*b.z + a.w*b.w);
}

__device__ __forceinline__ ushort_t f2bf(float f) {
    union { float f; uint_t u; } cv; cv.f = f;
    uint_t r = cv.u + 0x7fffu + ((cv.u >> 16) & 1u);
    return (ushort_t)(r >> 16);
}

__device__ __forceinline__ void gl2lds16(const ushort_t* g, ushort_t* l) {
    __builtin_amdgcn_global_load_lds(
        (const __attribute__((address_space(1))) unsigned int*)g,
        (__attribute__((address_space(3))) unsigned int*)l, 16, 0, 0);
}

__device__ __forceinline__ void gl2lds16f(const float* g, float* l) {
    __builtin_amdgcn_global_load_lds(
        (const __attribute__((address_space(1))) unsigned int*)g,
        (__attribute__((address_space(3))) unsigned int*)l, 16, 0, 0);
}

// ---------- Kernel 1: fused prep (qk | v | xt | border | wt) ----------
// grid 914: [0,128) qk, [128,384) v, [384,640) xt, [640,770) border, [770,914) wt
__global__ __launch_bounds__(256) void prep_kernel(
    const float* __restrict__ x, const float* __restrict__ xf, const float* __restrict__ xb,
    const float* __restrict__ Wq, const float* __restrict__ bq,
    const float* __restrict__ Wk, const float* __restrict__ bk,
    const float* __restrict__ Wv, const float* __restrict__ bv,
    const float* __restrict__ Wf,
    float* __restrict__ Qt, float* __restrict__ Kt, float* __restrict__ V,
    ushort_t* __restrict__ xsel, ushort_t* __restrict__ Wt)
{
    __shared__ __align__(16) unsigned char smem[16704];
    int bid = blockIdx.x;
    int tid = threadIdx.x;

    if (bid < 128) {
        // ---- qk: Q/K 1x1 conv -> [b][p][16] ----
        float* sW = (float*)smem;          // 16*128
        float* sB = sW + 2048;             // 16
        bool isQ = bid < 64;
        const float* src  = isQ ? xf : x;
        const float* W    = isQ ? Wq : Wk;
        const float* bias = isQ ? bq : bk;
        float* dst        = isQ ? Qt : Kt;
        for (int e = tid; e < 2048; e += 256) sW[e] = W[e];
        if (tid < 16) sB[tid] = bias[tid];
        __syncthreads();

        int pg = (bid & 63) * 256 + tid;
        int b = pg >> 12, p = pg & 4095;
        const float* sp = src + (size_t)b * CC * HW + p;

        float acc[16];
        #pragma unroll
        for (int o = 0; o < 16; o++) acc[o] = sB[o];
        for (int c4 = 0; c4 < 128; c4 += 4) {
            float x0 = sp[(c4+0)*HW];
            float x1 = sp[(c4+1)*HW];
            float x2 = sp[(c4+2)*HW];
            float x3 = sp[(c4+3)*HW];
            #pragma unroll
            for (int o = 0; o < 16; o++) {
                float4 w = *(const float4*)&sW[o*128 + c4];
                acc[o] += w.x*x0 + w.y*x1 + w.z*x2 + w.w*x3;
            }
        }
        float4* outp = (float4*)(dst + (size_t)pg * 16);
        outp[0] = make_float4(acc[0],acc[1],acc[2],acc[3]);
        outp[1] = make_float4(acc[4],acc[5],acc[6],acc[7]);
        outp[2] = make_float4(acc[8],acc[9],acc[10],acc[11]);
        outp[3] = make_float4(acc[12],acc[13],acc[14],acc[15]);
    } else if (bid < 384) {
        // ---- v: V = Wv * x_backward + bv, [b][c][p] ----
        float* sW = (float*)smem;          // 32*128
        int vbid = bid - 128;
        int b = vbid >> 6, og = (vbid >> 4) & 3, pt = vbid & 15;
        for (int e = tid; e < 4096; e += 256) sW[e] = Wv[og*4096 + e];
        __syncthreads();

        int oz = tid >> 7, pz = tid & 127;
        int p0 = pt*256 + pz, p1 = p0 + 128;
        const float* sp = xb + (size_t)b * CC * HW;

        float acc0[16], acc1[16];
        #pragma unroll
        for (int j = 0; j < 16; j++) { acc0[j] = 0.f; acc1[j] = 0.f; }
        for (int c4 = 0; c4 < 128; c4 += 4) {
            float a0 = sp[(c4+0)*HW + p0], a1 = sp[(c4+1)*HW + p0];
            float a2 = sp[(c4+2)*HW + p0], a3 = sp[(c4+3)*HW + p0];
            float b0 = sp[(c4+0)*HW + p1], b1 = sp[(c4+1)*HW + p1];
            float b2 = sp[(c4+2)*HW + p1], b3 = sp[(c4+3)*HW + p1];
            #pragma unroll
            for (int j = 0; j < 16; j++) {
                float4 w = *(const float4*)&sW[(oz*16 + j)*128 + c4];
                acc0[j] += w.x*a0 + w.y*a1 + w.z*a2 + w.w*a3;
                acc1[j] += w.x*b0 + w.y*b1 + w.z*b2 + w.w*b3;
            }
        }
        #pragma unroll
        for (int j = 0; j < 16; j++) {
            int o = og*32 + oz*16 + j;
            float bb = bv[o];
            V[(((size_t)b*CC + o)<<12) + p0] = acc0[j] + bb;
            V[(((size_t)b*CC + o)<<12) + p1] = acc1[j] + bb;
        }
    } else if (bid < 640) {
        // ---- xt: x f32 [c][y][x] -> xsel[b][y+1][x+1][c] bf16 (c<128) ----
        ushort_t* sT = (ushort_t*)smem;    // 64*130
        int xbid = bid - 384;
        int b = xbid >> 6, y = xbid & 63;
        int cq = tid >> 6, xx = tid & 63;
        const float* src = x + ((size_t)b << 19) + (y << 6) + xx;
        #pragma unroll 4
        for (int k = 0; k < 32; k++) {
            int c = cq*32 + k;
            sT[xx*130 + c] = f2bf(src[(size_t)c << 12]);
        }
        __syncthreads();
        uint_t* dst = (uint_t*)(xsel + ((size_t)(b*4356 + (y+1)*66 + 1))*256);
        #pragma unroll
        for (int k = 0; k < 16; k++) {
            int idx = k*256 + tid;
            int s = idx >> 6, u = idx & 63;
            uint_t v = *(const uint_t*)&sT[s*130 + u*2];
            dst[s*128 + u] = v;
        }
    } else if (bid < 770) {
        // ---- border: zero 66x66 border sites of xsel ----
        int g = (bid - 640) * 256 + tid;
        if (g < 33280) {
            int b = g / 8320;
            int rem = g - b * 8320;
            int si = rem >> 5;
            int ch = rem & 31;
            int y, xx;
            if (si < 66)      { y = 0;  xx = si; }
            else if (si < 132){ y = 65; xx = si - 66; }
            else { int t = si - 132; y = 1 + (t >> 1); xx = (t & 1) ? 65 : 0; }
            int site = y * 66 + xx;
            uint4* dst = (uint4*)(xsel + ((size_t)(b*4356 + site))*256);
            dst[ch] = make_uint4(0,0,0,0);
        }
    } else {
        // ---- wt: Wf f32 -> bf16 [og][cb][tap][o32][ci32] ----
        int t = (bid - 770) * 256 + tid;
        if (t < 36864) {
            int cg = t & 3;
            int o = (t >> 2) & 31;
            int tc = t >> 7;
            int tap = tc % 9;
            int rest = tc / 9;
            int cb = rest & 7, og = rest >> 3;
            union { ushort_t s[8]; uint4 v; } pk;
            #pragma unroll
            for (int j = 0; j < 8; j++) {
                int ci = cg*8 + j;
                pk.s[j] = f2bf(Wf[(size_t)(og*32 + o)*2304 + (cb*32 + ci)*9 + tap]);
            }
            *(uint4*)(Wt + (size_t)t*8) = pk.v;
        }
    }
}

// ---------- Kernel 2: fused max/argmax over q of K[k].Q[q] ----------
// grid 512 = b(4) x kt(64) x qh(2); block 512 = 8 waves; 64 k/block, 2048 q/block.
// Lane holds 4 K-vectors; 32 q-streams; Q double-buffered in LDS.
#define QCHUNK 256
__global__ __launch_bounds__(512, 4) void att_kernel(
    const float* __restrict__ Qt, const float* __restrict__ Kt,
    float* __restrict__ pmax, int* __restrict__ pidx)
{
    __shared__ __align__(16) float sQ[2][QCHUNK*16];   // 32 KB
    __shared__ float sM[64][33];
    __shared__ int   sI[64][33];

    int bid = blockIdx.x;
    int qh = bid & 1;
    int kt = (bid >> 1) & 63;
    int b  = bid >> 7;
    int tid = threadIdx.x;
    int wave = tid >> 6, lane = tid & 63;
    int kk = lane & 15;
    int lg = lane >> 4;
    int stream = wave*4 + lg;

    // 4 K vectors in registers (64 floats)
    const float4* Kp = (const float4*)(Kt + ((size_t)(b*HW) + kt*64 + kk*4)*16);
    float4 k0[4], k1[4], k2[4], k3[4];
    #pragma unroll
    for (int j = 0; j < 4; j++) { k0[j]=Kp[j]; k1[j]=Kp[4+j]; k2[j]=Kp[8+j]; k3[j]=Kp[12+j]; }

    const float* qsrc = Qt + ((size_t)(b*HW) + qh*2048)*16;

    // stage chunk 0 (16 regions of 1 KiB)
    gl2lds16f(qsrc + (wave*2  )*256 + lane*4, &sQ[0][(wave*2  )*256]);
    gl2lds16f(qsrc + (wave*2+1)*256 + lane*4, &sQ[0][(wave*2+1)*256]);

    float m0=-1e30f, m1=-1e30f, m2=-1e30f, m3=-1e30f;
    int i0=0, i1=0, i2=0, i3=0;

    for (int c = 0; c < 8; c++) {
        __syncthreads();                        // drains chunk-c loads
        if (c < 7) {
            const float* g = qsrc + (c+1)*(QCHUNK*16);
            int nb = (c+1) & 1;
            gl2lds16f(g + (wave*2  )*256 + lane*4, &sQ[nb][(wave*2  )*256]);
            gl2lds16f(g + (wave*2+1)*256 + lane*4, &sQ[nb][(wave*2+1)*256]);
        }
        const float* buf = sQ[c & 1];
        #pragma unroll
        for (int it = 0; it < 8; it++) {
            int ql = it*32 + stream;
            const float4* Qp4 = (const float4*)&buf[ql*16];
            float4 qa = Qp4[0], qb = Qp4[1], qc = Qp4[2], qd = Qp4[3];
            int q = qh*2048 + c*QCHUNK + ql;
            float d0 = (dot4(k0[0],qa) + dot4(k0[1],qb)) + (dot4(k0[2],qc) + dot4(k0[3],qd));
            float d1 = (dot4(k1[0],qa) + dot4(k1[1],qb)) + (dot4(k1[2],qc) + dot4(k1[3],qd));
            float d2 = (dot4(k2[0],qa) + dot4(k2[1],qb)) + (dot4(k2[2],qc) + dot4(k2[3],qd));
            float d3 = (dot4(k3[0],qa) + dot4(k3[1],qb)) + (dot4(k3[2],qc) + dot4(k3[3],qd));
            if (d0 > m0) { m0 = d0; i0 = q; }   // q ascending within stream
            if (d1 > m1) { m1 = d1; i1 = q; }
            if (d2 > m2) { m2 = d2; i2 = q; }
            if (d3 > m3) { m3 = d3; i3 = q; }
        }
    }

    sM[kk*4  ][stream] = m0;  sI[kk*4  ][stream] = i0;
    sM[kk*4+1][stream] = m1;  sI[kk*4+1][stream] = i1;
    sM[kk*4+2][stream] = m2;  sI[kk*4+2][stream] = i2;
    sM[kk*4+3][stream] = m3;  sI[kk*4+3][stream] = i3;
    __syncthreads();
    if (tid < 64) {
        float m = sM[tid][0]; int i = sI[tid][0];
        #pragma unroll 8
        for (int s = 1; s < 32; s++) {
            float mm = sM[tid][s]; int ii = sI[tid][s];
            if (mm > m || (mm == m && ii < i)) { m = mm; i = ii; }  // first-occurrence
        }
        int kglob = kt*64 + tid;
        pmax[((qh*4 + b) << 12) + kglob] = m;
        pidx[((qh*4 + b) << 12) + kglob] = i;
    }
}

// ---------- Kernel 3: combine halves + gather V columns -> xsel bf16 ----------
// grid 256 = b(4) x pt(64); thread: (pp=tid>>2, cq=tid&3) -> 32 channels
__global__ __launch_bounds__(256) void gather_kernel(
    const float* __restrict__ V, const float* __restrict__ pmax,
    const int* __restrict__ pidx, float* __restrict__ maxv,
    ushort_t* __restrict__ xsel)
{
    int bid = blockIdx.x;
    int b = bid >> 6, pt = bid & 63;
    int tid = threadIdx.x;
    int pp = tid >> 2, cq = tid & 3;
    int p = pt*64 + pp;

    float m0 = pmax[(b << 12) + p];
    int   j0 = pidx[(b << 12) + p];
    float m1 = pmax[((4 + b) << 12) + p];
    int   j1 = pidx[((4 + b) << 12) + p];
    float m = m0; int ip = j0;
    if (m1 > m) { m = m1; ip = j1; }          // j1 > j0 always: tie keeps first
    if (cq == 0) maxv[(b << 12) + p] = m;

    const float* vb = V + ((size_t)b << 19) + ip;
    int site = ((p >> 6) + 1)*66 + (p & 63) + 1;
    ushort_t* dst = xsel + ((size_t)(b*4356 + site))*256 + 128 + cq*32;
    #pragma unroll
    for (int k = 0; k < 4; k++) {
        union { ushort_t s[8]; uint4 v; } pk;
        #pragma unroll
        for (int j = 0; j < 8; j++) {
            int c = cq*32 + k*8 + j;
            pk.s[j] = f2bf(vb[(size_t)c << 12]);
        }
        *(uint4*)(dst + k*8) = pk.v;
    }
}

// ---------- Kernel 4: 3x3 conv as bf16 MFMA shift-GEMM ----------
__global__ __launch_bounds__(256) void conv_kernel(
    const float* __restrict__ x, const ushort_t* __restrict__ xsel,
    const ushort_t* __restrict__ Wt, const float* __restrict__ bf,
    const float* __restrict__ maxv, float* __restrict__ out)
{
    __shared__ __align__(16) ushort_t sIn[336*32];
    __shared__ __align__(16) ushort_t sW[9*32*32];

    int bid = blockIdx.x;
    int og = bid & 3, tx = (bid >> 2) & 3, ty = (bid >> 4) & 3, b = bid >> 6;
    int tid = threadIdx.x;
    int wave = tid >> 6, lane = tid & 63;
    int l15 = lane & 15, quad = lane >> 4;

    const ushort_t* xsel_base = xsel + ((size_t)(b*4356 + (ty*16)*66 + tx*16))*256;
    const ushort_t* wt_base   = Wt + (size_t)og*8*9216;

    f32x4 acc[4][2];
    #pragma unroll
    for (int mi = 0; mi < 4; mi++)
        #pragma unroll
        for (int ni = 0; ni < 2; ni++) acc[mi][ni] = (f32x4)0.f;

    int l4q = lane >> 2, l4 = lane & 3;

    for (int cb = 0; cb < 8; cb++) {
        if (cb) __syncthreads();
        for (int r = wave; r < 21; r += 4) {
            int site = r*16 + l4q;
            int iy = site / 18, ix = site - iy*18;
            const ushort_t* g = xsel_base + (size_t)(iy*66 + ix)*256 + cb*32 + l4*8;
            gl2lds16(g, &sIn[r*512]);
        }
        for (int r = wave; r < 18; r += 4) {
            const ushort_t* g = wt_base + (size_t)cb*9216 + r*512 + lane*8;
            gl2lds16(g, &sW[r*512]);
        }
        __syncthreads();

        #pragma unroll
        for (int tap = 0; tap < 9; tap++) {
            const int dy = tap / 3, dx = tap % 3;
            short8 B0 = *(const short8*)&sW[(tap*32 +      l15)*32 + quad*8];
            short8 B1 = *(const short8*)&sW[(tap*32 + 16 + l15)*32 + quad*8];
            #pragma unroll
            for (int mi = 0; mi < 4; mi++) {
                int row = wave*4 + mi + dy;
                short8 A = *(const short8*)&sIn[(row*18 + l15 + dx)*32 + quad*8];
                acc[mi][0] = __builtin_amdgcn_mfma_f32_16x16x32_bf16(A, B0, acc[mi][0], 0, 0, 0);
                acc[mi][1] = __builtin_amdgcn_mfma_f32_16x16x32_bf16(A, B1, acc[mi][1], 0, 0, 0);
            }
        }
    }

    int y0 = ty*16, x0 = tx*16;
    const float* xb_ = x   + ((size_t)b << 19);
    float*       ob  = out + ((size_t)b << 19);
    const float* mxb = maxv + (b << 12);
    #pragma unroll
    for (int mi = 0; mi < 4; mi++) {
        int y = y0 + wave*4 + mi;
        int p = (y << 6) + x0 + quad*4;
        float4 mv = *(const float4*)&mxb[p];
        #pragma unroll
        for (int ni = 0; ni < 2; ni++) {
            int o = og*32 + ni*16 + l15;
            float bfo = bf[o];
            float4 xv = *(const float4*)&xb_[((size_t)o << 12) + p];
            float4 r;
            r.x = xv.x + mv.x * (acc[mi][ni][0] + bfo);
            r.y = xv.y + mv.y * (acc[mi][ni][1] + bfo);
            r.z = xv.z + mv.z * (acc[mi][ni][2] + bfo);
            r.w = xv.w + mv.w * (acc[mi][ni][3] + bfo);
            *(float4*)&ob[((size_t)o << 12) + p] = r;
        }
    }
}

extern "C" void kernel_launch(void* const* d_in, const int* in_sizes, int n_in,
                              void* d_out, int out_size, void* d_ws, size_t ws_size,
                              hipStream_t stream) {
    (void)in_sizes; (void)n_in; (void)out_size; (void)ws_size;
    const float* x  = (const float*)d_in[0];
    const float* xf = (const float*)d_in[1];
    const float* xb = (const float*)d_in[2];
    const float* Wq = (const float*)d_in[3];
    const float* bq = (const float*)d_in[4];
    const float* Wk = (const float*)d_in[5];
    const float* bk = (const float*)d_in[6];
    const float* Wv = (const float*)d_in[7];
    const float* bv = (const float*)d_in[8];
    const float* Wf = (const float*)d_in[9];
    const float* bf = (const float*)d_in[10];
    float* out = (float*)d_out;

    float* ws   = (float*)d_ws;
    float* Qt   = ws;                         // 262144 f
    float* Kt   = Qt + 262144;                // 262144 f
    float* V    = Kt + 262144;                // 2097152 f
    float* pm   = V  + 2097152;               // 32768 f  (2 halves x 4 b x 4096 k)
    int*   pi   = (int*)(pm + 32768);         // 32768 i
    float* mx   = (float*)(pi + 32768);       // 16384 f
    ushort_t* xsel = (ushort_t*)(mx + 16384); // 4*4356*256 ush
    ushort_t* Wt   = xsel + 4460544 + 16384;  // 294912 ush

    hipLaunchKernelGGL(prep_kernel,   dim3(914), dim3(256), 0, stream,
                       x, xf, xb, Wq, bq, Wk, bk, Wv, bv, Wf, Qt, Kt, V, xsel, Wt);
    hipLaunchKernelGGL(att_kernel,    dim3(512), dim3(512), 0, stream, Qt, Kt, pm, pi);
    hipLaunchKernelGGL(gather_kernel, dim3(256), dim3(256), 0, stream, V, pm, pi, mx, xsel);
    hipLaunchKernelGGL(conv_kernel,   dim3(256), dim3(256), 0, stream, x, xsel, Wt, bf, mx, out);
}

// Round 6
// 220.202 us; speedup vs baseline: 1.2687x; 1.2687x over previous
//
#include <hip/hip_runtime.h>

#define HW 4096
#define CC 128
#define MARGIN 2e-3f

typedef unsigned short ushort_t;
typedef unsigned int uint_t;
typedef __attribute__((ext_vector_type(8))) short short8;
typedef __attribute__((ext_vector_type(4))) float f32x4;

__device__ __forceinline__ float dot4(float4 a, float4 b) {
    return (a.x*b.x + a.y*b.y) + (a.z*b.z + a.w*b.w);
}

__device__ __forceinline__ ushort_t f2bf(float f) {
    union { float f; uint_t u; } cv; cv.f = f;
    uint_t r = cv.u + 0x7fffu + ((cv.u >> 16) & 1u);
    return (ushort_t)(r >> 16);
}

__device__ __forceinline__ float bf2f(ushort_t h) {
    union { uint_t u; float f; } cv; cv.u = ((uint_t)h) << 16;
    return cv.f;
}

__device__ __forceinline__ void gl2lds16(const ushort_t* g, ushort_t* l) {
    __builtin_amdgcn_global_load_lds(
        (const __attribute__((address_space(1))) unsigned int*)g,
        (__attribute__((address_space(3))) unsigned int*)l, 16, 0, 0);
}

// ---------- Kernel 1: fused prep (qk | v | xt | border | wt) ----------
// grid 914: [0,128) qk, [128,384) v, [384,640) xt, [640,770) border, [770,914) wt
__global__ __launch_bounds__(256) void prep_kernel(
    const float* __restrict__ x, const float* __restrict__ xf, const float* __restrict__ xb,
    const float* __restrict__ Wq, const float* __restrict__ bq,
    const float* __restrict__ Wk, const float* __restrict__ bk,
    const float* __restrict__ Wv, const float* __restrict__ bv,
    const float* __restrict__ Wf,
    float* __restrict__ Qt, float* __restrict__ Kt, float* __restrict__ V,
    ushort_t* __restrict__ xsel, ushort_t* __restrict__ Wt)
{
    __shared__ __align__(16) unsigned char smem[16704];
    int bid = blockIdx.x;
    int tid = threadIdx.x;

    if (bid < 128) {
        float* sW = (float*)smem;
        float* sB = sW + 2048;
        bool isQ = bid < 64;
        const float* src  = isQ ? xf : x;
        const float* W    = isQ ? Wq : Wk;
        const float* bias = isQ ? bq : bk;
        float* dst        = isQ ? Qt : Kt;
        for (int e = tid; e < 2048; e += 256) sW[e] = W[e];
        if (tid < 16) sB[tid] = bias[tid];
        __syncthreads();

        int pg = (bid & 63) * 256 + tid;
        int b = pg >> 12, p = pg & 4095;
        const float* sp = src + (size_t)b * CC * HW + p;

        float acc[16];
        #pragma unroll
        for (int o = 0; o < 16; o++) acc[o] = sB[o];
        for (int c4 = 0; c4 < 128; c4 += 4) {
            float x0 = sp[(c4+0)*HW];
            float x1 = sp[(c4+1)*HW];
            float x2 = sp[(c4+2)*HW];
            float x3 = sp[(c4+3)*HW];
            #pragma unroll
            for (int o = 0; o < 16; o++) {
                float4 w = *(const float4*)&sW[o*128 + c4];
                acc[o] += w.x*x0 + w.y*x1 + w.z*x2 + w.w*x3;
            }
        }
        float4* outp = (float4*)(dst + (size_t)pg * 16);
        outp[0] = make_float4(acc[0],acc[1],acc[2],acc[3]);
        outp[1] = make_float4(acc[4],acc[5],acc[6],acc[7]);
        outp[2] = make_float4(acc[8],acc[9],acc[10],acc[11]);
        outp[3] = make_float4(acc[12],acc[13],acc[14],acc[15]);
    } else if (bid < 384) {
        float* sW = (float*)smem;
        int vbid = bid - 128;
        int b = vbid >> 6, og = (vbid >> 4) & 3, pt = vbid & 15;
        for (int e = tid; e < 4096; e += 256) sW[e] = Wv[og*4096 + e];
        __syncthreads();

        int oz = tid >> 7, pz = tid & 127;
        int p0 = pt*256 + pz, p1 = p0 + 128;
        const float* sp = xb + (size_t)b * CC * HW;

        float acc0[16], acc1[16];
        #pragma unroll
        for (int j = 0; j < 16; j++) { acc0[j] = 0.f; acc1[j] = 0.f; }
        for (int c4 = 0; c4 < 128; c4 += 4) {
            float a0 = sp[(c4+0)*HW + p0], a1 = sp[(c4+1)*HW + p0];
            float a2 = sp[(c4+2)*HW + p0], a3 = sp[(c4+3)*HW + p0];
            float b0 = sp[(c4+0)*HW + p1], b1 = sp[(c4+1)*HW + p1];
            float b2 = sp[(c4+2)*HW + p1], b3 = sp[(c4+3)*HW + p1];
            #pragma unroll
            for (int j = 0; j < 16; j++) {
                float4 w = *(const float4*)&sW[(oz*16 + j)*128 + c4];
                acc0[j] += w.x*a0 + w.y*a1 + w.z*a2 + w.w*a3;
                acc1[j] += w.x*b0 + w.y*b1 + w.z*b2 + w.w*b3;
            }
        }
        #pragma unroll
        for (int j = 0; j < 16; j++) {
            int o = og*32 + oz*16 + j;
            float bb = bv[o];
            V[(((size_t)b*CC + o)<<12) + p0] = acc0[j] + bb;
            V[(((size_t)b*CC + o)<<12) + p1] = acc1[j] + bb;
        }
    } else if (bid < 640) {
        ushort_t* sT = (ushort_t*)smem;
        int xbid = bid - 384;
        int b = xbid >> 6, y = xbid & 63;
        int cq = tid >> 6, xx = tid & 63;
        const float* src = x + ((size_t)b << 19) + (y << 6) + xx;
        #pragma unroll 4
        for (int k = 0; k < 32; k++) {
            int c = cq*32 + k;
            sT[xx*130 + c] = f2bf(src[(size_t)c << 12]);
        }
        __syncthreads();
        uint_t* dst = (uint_t*)(xsel + ((size_t)(b*4356 + (y+1)*66 + 1))*256);
        #pragma unroll
        for (int k = 0; k < 16; k++) {
            int idx = k*256 + tid;
            int s = idx >> 6, u = idx & 63;
            uint_t v = *(const uint_t*)&sT[s*130 + u*2];
            dst[s*128 + u] = v;
        }
    } else if (bid < 770) {
        int g = (bid - 640) * 256 + tid;
        if (g < 33280) {
            int b = g / 8320;
            int rem = g - b * 8320;
            int si = rem >> 5;
            int ch = rem & 31;
            int y, xx;
            if (si < 66)      { y = 0;  xx = si; }
            else if (si < 132){ y = 65; xx = si - 66; }
            else { int t = si - 132; y = 1 + (t >> 1); xx = (t & 1) ? 65 : 0; }
            int site = y * 66 + xx;
            uint4* dst = (uint4*)(xsel + ((size_t)(b*4356 + site))*256);
            dst[ch] = make_uint4(0,0,0,0);
        }
    } else {
        int t = (bid - 770) * 256 + tid;
        if (t < 36864) {
            int cg = t & 3;
            int o = (t >> 2) & 31;
            int tc = t >> 7;
            int tap = tc % 9;
            int rest = tc / 9;
            int cb = rest & 7, og = rest >> 3;
            union { ushort_t s[8]; uint4 v; } pk;
            #pragma unroll
            for (int j = 0; j < 8; j++) {
                int ci = cg*8 + j;
                pk.s[j] = f2bf(Wf[(size_t)(og*32 + o)*2304 + (cb*32 + ci)*9 + tap]);
            }
            *(uint4*)(Wt + (size_t)t*8) = pk.v;
        }
    }
}

// ---------- Kernel 2: build bf16 3-term splits for MFMA scores ----------
// grid 320: [0,256) Qsplit rows, [256,320) K B-fragment arrays
// Qs row (64 sh): [qh(16) | qm(16) | qh(16) | ql(16)]
// KB per (b,kt16): 3 passes x [n=16][s=32]: p0=[kh|kh], p1=[km|km], p2=[kl|kh]
__global__ __launch_bounds__(256) void prep2_kernel(
    const float* __restrict__ Qt, const float* __restrict__ Kt,
    ushort_t* __restrict__ Qs, ushort_t* __restrict__ KB)
{
    int bid = blockIdx.x, tid = threadIdx.x;
    if (bid < 256) {
        int row = bid*64 + (tid >> 2);     // b*4096+q
        int j = tid & 3;
        float4 v = *(const float4*)(Qt + (size_t)row*16 + j*4);
        float vv[4] = {v.x, v.y, v.z, v.w};
        union { ushort_t s[4]; uint2 u; } ph, pm_, pl;
        #pragma unroll
        for (int d = 0; d < 4; d++) {
            ushort_t hh = f2bf(vv[d]);
            float r1 = vv[d] - bf2f(hh);
            ushort_t mm = f2bf(r1);
            float r2 = r1 - bf2f(mm);
            ph.s[d] = hh; pm_.s[d] = mm; pl.s[d] = f2bf(r2);
        }
        ushort_t* out = Qs + (size_t)row*64;
        *(uint2*)(out + j*4)      = ph.u;
        *(uint2*)(out + 16 + j*4) = pm_.u;
        *(uint2*)(out + 32 + j*4) = ph.u;
        *(uint2*)(out + 48 + j*4) = pl.u;
    } else {
        int u = (bid - 256)*16 + (tid >> 4);   // 0..1023 = b*256+kt16
        int n = tid & 15;
        int b = u >> 8, kt = u & 255;
        const float* kr = Kt + ((size_t)(b*4096 + kt*16 + n))*16;
        union { ushort_t s[16]; uint4 v[2]; } kh, km, kl;
        #pragma unroll
        for (int d = 0; d < 16; d++) {
            float f = kr[d];
            ushort_t hh = f2bf(f);
            float r1 = f - bf2f(hh);
            ushort_t mm = f2bf(r1);
            float r2 = r1 - bf2f(mm);
            kh.s[d] = hh; km.s[d] = mm; kl.s[d] = f2bf(r2);
        }
        ushort_t* o = KB + ((size_t)u*3)*512 + n*32;
        uint4* o4 = (uint4*)o;
        o4[0] = kh.v[0]; o4[1] = kh.v[1]; o4[2] = kh.v[0]; o4[3] = kh.v[1];
        uint4* o4b = (uint4*)(o + 512);
        o4b[0] = km.v[0]; o4b[1] = km.v[1]; o4b[2] = km.v[0]; o4b[3] = km.v[1];
        uint4* o4c = (uint4*)(o + 1024);
        o4c[0] = kl.v[0]; o4c[1] = kl.v[1]; o4c[2] = kh.v[0]; o4c[3] = kh.v[1];
    }
}

// ---------- Kernel 3: MFMA max/argmax with top-2 margin tracking ----------
// grid 512 = qh(2) x kg(64) x b(4); block 512 = 8 waves.
// Block: 64 k (4 ktiles of 16) x 2048 q. Wave: 4 ktiles x 256 q (16 qtiles).
__global__ __launch_bounds__(512) void att_kernel(
    const ushort_t* __restrict__ Qs, const ushort_t* __restrict__ KB,
    float* __restrict__ pm1, int* __restrict__ pi1, float* __restrict__ pm2)
{
    __shared__ float sM1[64*33];
    __shared__ int   sI1[64*33];
    __shared__ float sM2[64*33];

    int bid = blockIdx.x;
    int qh = bid & 1, kg = (bid >> 1) & 63, b = bid >> 7;
    int tid = threadIdx.x;
    int wave = tid >> 6, lane = tid & 63;
    int l15 = lane & 15, quad = lane >> 4;

    // B fragments (registers): 4 ktiles x 3 passes
    short8 Bf[4][3];
    const ushort_t* kb = KB + ((size_t)((b*256 + kg*4)*3))*512 + l15*32 + quad*8;
    #pragma unroll
    for (int t = 0; t < 4; t++)
        #pragma unroll
        for (int p = 0; p < 3; p++)
            Bf[t][p] = *(const short8*)(kb + (size_t)(t*3 + p)*512);

    const ushort_t* qbase = Qs + ((size_t)(b*4096 + qh*2048 + wave*256 + l15))*64 + quad*8;

    float m1[4], m2[4]; int i1[4];
    #pragma unroll
    for (int t = 0; t < 4; t++) { m1[t] = -1e30f; m2[t] = -1e30f; i1[t] = 0; }

    for (int it = 0; it < 16; it++) {
        const ushort_t* aptr = qbase + it*1024;        // 16 rows x 64 sh
        short8 A1 = *(const short8*)aptr;              // [qh|qm] slice
        short8 A2 = *(const short8*)(aptr + 32);       // [qh|ql] slice
        f32x4 acc[4];
        #pragma unroll
        for (int t = 0; t < 4; t++) {
            acc[t] = (f32x4)0.f;
            acc[t] = __builtin_amdgcn_mfma_f32_16x16x32_bf16(A1, Bf[t][0], acc[t], 0, 0, 0);
            acc[t] = __builtin_amdgcn_mfma_f32_16x16x32_bf16(A1, Bf[t][1], acc[t], 0, 0, 0);
            acc[t] = __builtin_amdgcn_mfma_f32_16x16x32_bf16(A2, Bf[t][2], acc[t], 0, 0, 0);
        }
        int q0 = qh*2048 + wave*256 + it*16 + quad*4;
        #pragma unroll
        for (int r = 0; r < 4; r++) {
            int cand = q0 + r;
            #pragma unroll
            for (int t = 0; t < 4; t++) {
                float d = acc[t][r];
                float old1 = m1[t];
                bool gt = d > old1;                 // ascending q: strict '>' = first occurrence
                m1[t] = gt ? d : old1;
                i1[t] = gt ? cand : i1[t];
                m2[t] = fmaxf(m2[t], fminf(d, old1));
            }
        }
    }

    #pragma unroll
    for (int t = 0; t < 4; t++) {
        int kl_ = t*16 + l15;
        int slot = wave*4 + quad;
        sM1[kl_*33 + slot] = m1[t];
        sI1[kl_*33 + slot] = i1[t];
        sM2[kl_*33 + slot] = m2[t];
    }
    __syncthreads();
    if (tid < 64) {
        float M1 = -1e30f; int I1 = 0x7fffffff;
        for (int s = 0; s < 32; s++) {
            float m = sM1[tid*33 + s]; int i = sI1[tid*33 + s];
            if (m > M1 || (m == M1 && i < I1)) { M1 = m; I1 = i; }
        }
        float M2 = -1e30f;
        for (int s = 0; s < 32; s++) {
            float m = sM1[tid*33 + s]; int i = sI1[tid*33 + s];
            float cnd = (i == I1) ? sM2[tid*33 + s] : m;
            M2 = fmaxf(M2, cnd);
        }
        int out = ((qh*4 + b) << 12) + kg*64 + tid;
        pm1[out] = M1; pi1[out] = I1; pm2[out] = M2;
    }
}

// ---------- Kernel 4: combine halves; exact f32 rescan where margin < MARGIN ----------
// grid 64 x 256: block handles 256 rows
__global__ __launch_bounds__(256) void fixup_kernel(
    const float* __restrict__ Qt, const float* __restrict__ Kt,
    const float* __restrict__ pm1, const int* __restrict__ pi1,
    const float* __restrict__ pm2,
    float* __restrict__ maxv, int* __restrict__ idxv)
{
    __shared__ int sList[256];
    __shared__ int sCount;
    __shared__ float sRm[256];
    __shared__ int   sRi[256];
    int bid = blockIdx.x, tid = threadIdx.x;
    if (tid == 0) sCount = 0;
    __syncthreads();
    int row = bid*256 + tid;
    int b = row >> 12, k = row & 4095;
    float m1a = pm1[(b<<12)+k];     int i1a = pi1[(b<<12)+k];     float m2a = pm2[(b<<12)+k];
    float m1b = pm1[((4+b)<<12)+k]; int i1b = pi1[((4+b)<<12)+k]; float m2b = pm2[((4+b)<<12)+k];
    float M1, ru; int I1;
    if (m1b > m1a) { M1 = m1b; I1 = i1b; ru = fmaxf(m1a, fmaxf(m2a, m2b)); }
    else           { M1 = m1a; I1 = i1a; ru = fmaxf(m1b, fmaxf(m2a, m2b)); }
    if (M1 - ru >= MARGIN) {
        maxv[row] = M1; idxv[row] = I1;
    } else {
        int p = atomicAdd(&sCount, 1);
        sList[p] = row;
    }
    __syncthreads();
    int n = sCount;
    for (int e = 0; e < n; e++) {
        int r2 = sList[e];
        int b2 = r2 >> 12, k2 = r2 & 4095;
        const float4* Kp = (const float4*)(Kt + ((size_t)(b2*4096 + k2))*16);
        float4 ka = Kp[0], kbv = Kp[1], kc = Kp[2], kd = Kp[3];
        const float4* Qp = (const float4*)(Qt + ((size_t)b2*4096)*16);
        float m = -1e30f; int i = 0;
        #pragma unroll 4
        for (int j = 0; j < 16; j++) {
            int q = tid*16 + j;
            float4 qa = Qp[q*4+0], qb = Qp[q*4+1], qc = Qp[q*4+2], qd = Qp[q*4+3];
            float d = (dot4(ka,qa) + dot4(kbv,qb)) + (dot4(kc,qc) + dot4(kd,qd));
            if (d > m) { m = d; i = q; }
        }
        sRm[tid] = m; sRi[tid] = i;
        __syncthreads();
        if (tid == 0) {
            float M = sRm[0]; int I = sRi[0];
            for (int s = 1; s < 256; s++) {
                if (sRm[s] > M) { M = sRm[s]; I = sRi[s]; }
            }
            maxv[r2] = M; idxv[r2] = I;
        }
        __syncthreads();
    }
}

// ---------- Kernel 5: gather V columns -> xsel bf16 ----------
__global__ __launch_bounds__(256) void gather_kernel(
    const float* __restrict__ V, const int* __restrict__ idxv,
    ushort_t* __restrict__ xsel)
{
    int bid = blockIdx.x;
    int b = bid >> 6, pt = bid & 63;
    int tid = threadIdx.x;
    int pp = tid >> 2, cq = tid & 3;
    int p = pt*64 + pp;
    int ip = idxv[(b << 12) + p];
    const float* vb = V + ((size_t)b << 19) + ip;
    int site = ((p >> 6) + 1)*66 + (p & 63) + 1;
    ushort_t* dst = xsel + ((size_t)(b*4356 + site))*256 + 128 + cq*32;
    #pragma unroll
    for (int k = 0; k < 4; k++) {
        union { ushort_t s[8]; uint4 v; } pk;
        #pragma unroll
        for (int j = 0; j < 8; j++) {
            int c = cq*32 + k*8 + j;
            pk.s[j] = f2bf(vb[(size_t)c << 12]);
        }
        *(uint4*)(dst + k*8) = pk.v;
    }
}

// ---------- Kernel 6: 3x3 conv as bf16 MFMA shift-GEMM ----------
__global__ __launch_bounds__(256) void conv_kernel(
    const float* __restrict__ x, const ushort_t* __restrict__ xsel,
    const ushort_t* __restrict__ Wt, const float* __restrict__ bf,
    const float* __restrict__ maxv, float* __restrict__ out)
{
    __shared__ __align__(16) ushort_t sIn[336*32];
    __shared__ __align__(16) ushort_t sW[9*32*32];

    int bid = blockIdx.x;
    int og = bid & 3, tx = (bid >> 2) & 3, ty = (bid >> 4) & 3, b = bid >> 6;
    int tid = threadIdx.x;
    int wave = tid >> 6, lane = tid & 63;
    int l15 = lane & 15, quad = lane >> 4;

    const ushort_t* xsel_base = xsel + ((size_t)(b*4356 + (ty*16)*66 + tx*16))*256;
    const ushort_t* wt_base   = Wt + (size_t)og*8*9216;

    f32x4 acc[4][2];
    #pragma unroll
    for (int mi = 0; mi < 4; mi++)
        #pragma unroll
        for (int ni = 0; ni < 2; ni++) acc[mi][ni] = (f32x4)0.f;

    int l4q = lane >> 2, l4 = lane & 3;

    for (int cb = 0; cb < 8; cb++) {
        if (cb) __syncthreads();
        for (int r = wave; r < 21; r += 4) {
            int site = r*16 + l4q;
            int iy = site / 18, ix = site - iy*18;
            const ushort_t* g = xsel_base + (size_t)(iy*66 + ix)*256 + cb*32 + l4*8;
            gl2lds16(g, &sIn[r*512]);
        }
        for (int r = wave; r < 18; r += 4) {
            const ushort_t* g = wt_base + (size_t)cb*9216 + r*512 + lane*8;
            gl2lds16(g, &sW[r*512]);
        }
        __syncthreads();

        #pragma unroll
        for (int tap = 0; tap < 9; tap++) {
            const int dy = tap / 3, dx = tap % 3;
            short8 B0 = *(const short8*)&sW[(tap*32 +      l15)*32 + quad*8];
            short8 B1 = *(const short8*)&sW[(tap*32 + 16 + l15)*32 + quad*8];
            #pragma unroll
            for (int mi = 0; mi < 4; mi++) {
                int row = wave*4 + mi + dy;
                short8 A = *(const short8*)&sIn[(row*18 + l15 + dx)*32 + quad*8];
                acc[mi][0] = __builtin_amdgcn_mfma_f32_16x16x32_bf16(A, B0, acc[mi][0], 0, 0, 0);
                acc[mi][1] = __builtin_amdgcn_mfma_f32_16x16x32_bf16(A, B1, acc[mi][1], 0, 0, 0);
            }
        }
    }

    int y0 = ty*16, x0 = tx*16;
    const float* xb_ = x   + ((size_t)b << 19);
    float*       ob  = out + ((size_t)b << 19);
    const float* mxb = maxv + (b << 12);
    #pragma unroll
    for (int mi = 0; mi < 4; mi++) {
        int y = y0 + wave*4 + mi;
        int p = (y << 6) + x0 + quad*4;
        float4 mv = *(const float4*)&mxb[p];
        #pragma unroll
        for (int ni = 0; ni < 2; ni++) {
            int o = og*32 + ni*16 + l15;
            float bfo = bf[o];
            float4 xv = *(const float4*)&xb_[((size_t)o << 12) + p];
            float4 r;
            r.x = xv.x + mv.x * (acc[mi][ni][0] + bfo);
            r.y = xv.y + mv.y * (acc[mi][ni][1] + bfo);
            r.z = xv.z + mv.z * (acc[mi][ni][2] + bfo);
            r.w = xv.w + mv.w * (acc[mi][ni][3] + bfo);
            *(float4*)&ob[((size_t)o << 12) + p] = r;
        }
    }
}

extern "C" void kernel_launch(void* const* d_in, const int* in_sizes, int n_in,
                              void* d_out, int out_size, void* d_ws, size_t ws_size,
                              hipStream_t stream) {
    (void)in_sizes; (void)n_in; (void)out_size; (void)ws_size;
    const float* x  = (const float*)d_in[0];
    const float* xf = (const float*)d_in[1];
    const float* xb = (const float*)d_in[2];
    const float* Wq = (const float*)d_in[3];
    const float* bq = (const float*)d_in[4];
    const float* Wk = (const float*)d_in[5];
    const float* bk = (const float*)d_in[6];
    const float* Wv = (const float*)d_in[7];
    const float* bv = (const float*)d_in[8];
    const float* Wf = (const float*)d_in[9];
    const float* bf = (const float*)d_in[10];
    float* out = (float*)d_out;

    float* ws   = (float*)d_ws;
    float* Qt   = ws;                          // 262144 f
    float* Kt   = Qt + 262144;                 // 262144 f
    float* V    = Kt + 262144;                 // 2097152 f
    float* mx   = V  + 2097152;                // 16384 f
    int*   idxv = (int*)(mx + 16384);          // 16384 i
    float* pm1  = (float*)(idxv + 16384);      // 32768 f
    int*   pi1  = (int*)(pm1 + 32768);         // 32768 i
    float* pm2  = (float*)(pi1 + 32768);       // 32768 f
    ushort_t* Qs   = (ushort_t*)(pm2 + 32768); // 1048576 sh
    ushort_t* KB   = Qs + 1048576;             // 1572864 sh
    ushort_t* xsel = KB + 1572864;             // 4460544 sh
    ushort_t* Wt   = xsel + 4460544;           // 294912 sh

    hipLaunchKernelGGL(prep_kernel,   dim3(914), dim3(256), 0, stream,
                       x, xf, xb, Wq, bq, Wk, bk, Wv, bv, Wf, Qt, Kt, V, xsel, Wt);
    hipLaunchKernelGGL(prep2_kernel,  dim3(320), dim3(256), 0, stream, Qt, Kt, Qs, KB);
    hipLaunchKernelGGL(att_kernel,    dim3(512), dim3(512), 0, stream, Qs, KB, pm1, pi1, pm2);
    hipLaunchKernelGGL(fixup_kernel,  dim3(64),  dim3(256), 0, stream, Qt, Kt, pm1, pi1, pm2, mx, idxv);
    hipLaunchKernelGGL(gather_kernel, dim3(256), dim3(256), 0, stream, V, idxv, xsel);
    hipLaunchKernelGGL(conv_kernel,   dim3(256), dim3(256), 0, stream, x, xsel, Wt, bf, mx, out);
}

// Round 7
// 207.316 us; speedup vs baseline: 1.3476x; 1.0622x over previous
//
#include <hip/hip_runtime.h>

#define HW 4096
#define CC 128
#define MARGIN 2e-3f

typedef unsigned short ushort_t;
typedef unsigned int uint_t;
typedef __attribute__((ext_vector_type(8))) short short8;
typedef __attribute__((ext_vector_type(4))) float f32x4;

__device__ __forceinline__ float dot4(float4 a, float4 b) {
    return (a.x*b.x + a.y*b.y) + (a.z*b.z + a.w*b.w);
}

__device__ __forceinline__ ushort_t f2bf(float f) {
    union { float f; uint_t u; } cv; cv.f = f;
    uint_t r = cv.u + 0x7fffu + ((cv.u >> 16) & 1u);
    return (ushort_t)(r >> 16);
}

__device__ __forceinline__ float bf2f(ushort_t h) {
    union { uint_t u; float f; } cv; cv.u = ((uint_t)h) << 16;
    return cv.f;
}

__device__ __forceinline__ void store16(ushort_t* dst, const ushort_t* s) {
    union { ushort_t s[8]; uint4 v; } a, b;
    #pragma unroll
    for (int j = 0; j < 8; j++) { a.s[j] = s[j]; b.s[j] = s[8+j]; }
    *(uint4*)dst = a.v;
    *(uint4*)(dst + 8) = b.v;
}

__device__ __forceinline__ void gl2lds16(const ushort_t* g, ushort_t* l) {
    __builtin_amdgcn_global_load_lds(
        (const __attribute__((address_space(1))) unsigned int*)g,
        (__attribute__((address_space(3))) unsigned int*)l, 16, 0, 0);
}

// ---------- Kernel 1: fused prep (qk+split | v | xt | border | wt) ----------
// grid 690: [0,32) qk, [32,160) v, [160,416) xt, [416,546) border, [546,690) wt
__global__ __launch_bounds__(256) void prep_kernel(
    const float* __restrict__ x, const float* __restrict__ xf, const float* __restrict__ xb,
    const float* __restrict__ Wq, const float* __restrict__ bq,
    const float* __restrict__ Wk, const float* __restrict__ bk,
    const float* __restrict__ Wv, const float* __restrict__ bv,
    const float* __restrict__ Wf,
    float* __restrict__ Qt, float* __restrict__ Kt, float* __restrict__ V,
    ushort_t* __restrict__ Qs, ushort_t* __restrict__ KB,
    ushort_t* __restrict__ xsel, ushort_t* __restrict__ Wt)
{
    __shared__ __align__(16) unsigned char smem[16704];
    int bid = blockIdx.x;
    int tid = threadIdx.x;

    if (bid < 32) {
        // ---- qk: Q/K 1x1 conv -> Qt/Kt f32 [b][p][16] + bf16 split Qs/KB ----
        float* sW = (float*)smem;
        float* sB = sW + 2048;
        bool isQ = bid < 16;
        const float* src  = isQ ? xf : x;
        const float* W    = isQ ? Wq : Wk;
        const float* bias = isQ ? bq : bk;
        int sub = bid & 15;
        int b = sub >> 2, pt = sub & 3;
        for (int e = tid; e < 2048; e += 256) sW[e] = W[e];
        if (tid < 16) sB[tid] = bias[tid];
        __syncthreads();

        int p = pt*1024 + tid*4;
        const float* sp = src + (size_t)b * CC * HW + p;

        float4 acc[16];
        #pragma unroll
        for (int o = 0; o < 16; o++) { float bb = sB[o]; acc[o] = make_float4(bb,bb,bb,bb); }

        for (int c4 = 0; c4 < 128; c4 += 4) {
            float4 x0 = *(const float4*)&sp[(c4+0)*HW];
            float4 x1 = *(const float4*)&sp[(c4+1)*HW];
            float4 x2 = *(const float4*)&sp[(c4+2)*HW];
            float4 x3 = *(const float4*)&sp[(c4+3)*HW];
            #pragma unroll
            for (int o = 0; o < 16; o++) {
                float4 w = *(const float4*)&sW[o*128 + c4];
                acc[o].x += w.x*x0.x + w.y*x1.x + w.z*x2.x + w.w*x3.x;
                acc[o].y += w.x*x0.y + w.y*x1.y + w.z*x2.y + w.w*x3.y;
                acc[o].z += w.x*x0.z + w.y*x1.z + w.z*x2.z + w.w*x3.z;
                acc[o].w += w.x*x0.w + w.y*x1.w + w.z*x2.w + w.w*x3.w;
            }
        }

        float* dstF = isQ ? Qt : Kt;
        int pg = b*4096 + p;
        #pragma unroll
        for (int pp = 0; pp < 4; pp++) {
            float vd[16];
            #pragma unroll
            for (int o = 0; o < 16; o++)
                vd[o] = (pp==0) ? acc[o].x : (pp==1) ? acc[o].y : (pp==2) ? acc[o].z : acc[o].w;
            float4* df = (float4*)(dstF + (size_t)(pg + pp)*16);
            df[0] = make_float4(vd[0],vd[1],vd[2],vd[3]);
            df[1] = make_float4(vd[4],vd[5],vd[6],vd[7]);
            df[2] = make_float4(vd[8],vd[9],vd[10],vd[11]);
            df[3] = make_float4(vd[12],vd[13],vd[14],vd[15]);
            ushort_t h[16], m[16], l[16];
            #pragma unroll
            for (int d = 0; d < 16; d++) {
                h[d] = f2bf(vd[d]);
                float r1 = vd[d] - bf2f(h[d]);
                m[d] = f2bf(r1);
                l[d] = f2bf(r1 - bf2f(m[d]));
            }
            if (isQ) {
                ushort_t* o_ = Qs + (size_t)(pg + pp)*64;   // [h|m|h|l]
                store16(o_,      h);
                store16(o_ + 16, m);
                store16(o_ + 32, h);
                store16(o_ + 48, l);
            } else {
                int k = p + pp;
                int u = b*256 + (k >> 4);
                int n = k & 15;
                ushort_t* o_ = KB + (size_t)u*1536 + n*32;
                store16(o_,        h); store16(o_ + 16,   h);   // pass0 [kh|kh]
                store16(o_ + 512,  m); store16(o_ + 528,  m);   // pass1 [km|km]
                store16(o_ + 1024, l); store16(o_ + 1040, h);   // pass2 [kl|kh]
            }
        }
    } else if (bid < 160) {
        // ---- v: V = Wv * x_backward + bv, [b][c][p]; 4 pos/thread ----
        float* sW = (float*)smem;          // 32*128
        int vbid = bid - 32;
        int b = vbid >> 5, og = (vbid >> 3) & 3, pt = vbid & 7;
        for (int e = tid; e < 4096; e += 256) sW[e] = Wv[og*4096 + e];
        __syncthreads();

        int oz = tid >> 7, pz = tid & 127;
        int p = pt*512 + pz*4;
        const float* sp = xb + (size_t)b * CC * HW + p;

        float4 acc[16];
        #pragma unroll
        for (int j = 0; j < 16; j++) acc[j] = make_float4(0.f,0.f,0.f,0.f);

        for (int c4 = 0; c4 < 128; c4 += 4) {
            float4 x0 = *(const float4*)&sp[(c4+0)*HW];
            float4 x1 = *(const float4*)&sp[(c4+1)*HW];
            float4 x2 = *(const float4*)&sp[(c4+2)*HW];
            float4 x3 = *(const float4*)&sp[(c4+3)*HW];
            #pragma unroll
            for (int j = 0; j < 16; j++) {
                float4 w = *(const float4*)&sW[(oz*16 + j)*128 + c4];
                acc[j].x += w.x*x0.x + w.y*x1.x + w.z*x2.x + w.w*x3.x;
                acc[j].y += w.x*x0.y + w.y*x1.y + w.z*x2.y + w.w*x3.y;
                acc[j].z += w.x*x0.z + w.y*x1.z + w.z*x2.z + w.w*x3.z;
                acc[j].w += w.x*x0.w + w.y*x1.w + w.z*x2.w + w.w*x3.w;
            }
        }
        #pragma unroll
        for (int j = 0; j < 16; j++) {
            int o = og*32 + oz*16 + j;
            float bb = bv[o];
            float4 r = make_float4(acc[j].x+bb, acc[j].y+bb, acc[j].z+bb, acc[j].w+bb);
            *(float4*)&V[(((size_t)b*CC + o)<<12) + p] = r;
        }
    } else if (bid < 416) {
        // ---- xt: x f32 [c][y][x] -> xsel[b][y+1][x+1][c] bf16 (c<128) ----
        ushort_t* sT = (ushort_t*)smem;    // 64*130
        int xbid = bid - 160;
        int b = xbid >> 6, y = xbid & 63;
        int cq = tid >> 6, xx = tid & 63;
        const float* src = x + ((size_t)b << 19) + (y << 6) + xx;
        #pragma unroll 4
        for (int k = 0; k < 32; k++) {
            int c = cq*32 + k;
            sT[xx*130 + c] = f2bf(src[(size_t)c << 12]);
        }
        __syncthreads();
        uint_t* dst = (uint_t*)(xsel + ((size_t)(b*4356 + (y+1)*66 + 1))*256);
        #pragma unroll
        for (int k = 0; k < 16; k++) {
            int idx = k*256 + tid;
            int s = idx >> 6, u = idx & 63;
            uint_t v = *(const uint_t*)&sT[s*130 + u*2];
            dst[s*128 + u] = v;
        }
    } else if (bid < 546) {
        // ---- border: zero 66x66 border sites of xsel ----
        int g = (bid - 416) * 256 + tid;
        if (g < 33280) {
            int b = g / 8320;
            int rem = g - b * 8320;
            int si = rem >> 5;
            int ch = rem & 31;
            int y, xx;
            if (si < 66)      { y = 0;  xx = si; }
            else if (si < 132){ y = 65; xx = si - 66; }
            else { int t = si - 132; y = 1 + (t >> 1); xx = (t & 1) ? 65 : 0; }
            int site = y * 66 + xx;
            uint4* dst = (uint4*)(xsel + ((size_t)(b*4356 + site))*256);
            dst[ch] = make_uint4(0,0,0,0);
        }
    } else {
        // ---- wt: Wf f32 -> bf16 [og][cb][tap][o32][ci32] ----
        int t = (bid - 546) * 256 + tid;
        if (t < 36864) {
            int cg = t & 3;
            int o = (t >> 2) & 31;
            int tc = t >> 7;
            int tap = tc % 9;
            int rest = tc / 9;
            int cb = rest & 7, og = rest >> 3;
            union { ushort_t s[8]; uint4 v; } pk;
            #pragma unroll
            for (int j = 0; j < 8; j++) {
                int ci = cg*8 + j;
                pk.s[j] = f2bf(Wf[(size_t)(og*32 + o)*2304 + (cb*32 + ci)*9 + tap]);
            }
            *(uint4*)(Wt + (size_t)t*8) = pk.v;
        }
    }
}

// ---------- Kernel 2: MFMA max/argmax with top-2 margin tracking ----------
// grid 512 = qh(2) x kg(64) x b(4); block 512 = 8 waves.
__global__ __launch_bounds__(512) void att_kernel(
    const ushort_t* __restrict__ Qs, const ushort_t* __restrict__ KB,
    float* __restrict__ pm1, int* __restrict__ pi1, float* __restrict__ pm2)
{
    __shared__ float sM1[64*33];
    __shared__ int   sI1[64*33];
    __shared__ float sM2[64*33];

    int bid = blockIdx.x;
    int qh = bid & 1, kg = (bid >> 1) & 63, b = bid >> 7;
    int tid = threadIdx.x;
    int wave = tid >> 6, lane = tid & 63;
    int l15 = lane & 15, quad = lane >> 4;

    short8 Bf[4][3];
    const ushort_t* kb = KB + ((size_t)((b*256 + kg*4)*3))*512 + l15*32 + quad*8;
    #pragma unroll
    for (int t = 0; t < 4; t++)
        #pragma unroll
        for (int p = 0; p < 3; p++)
            Bf[t][p] = *(const short8*)(kb + (size_t)(t*3 + p)*512);

    const ushort_t* qbase = Qs + ((size_t)(b*4096 + qh*2048 + wave*256 + l15))*64 + quad*8;

    float m1[4], m2[4]; int i1[4];
    #pragma unroll
    for (int t = 0; t < 4; t++) { m1[t] = -1e30f; m2[t] = -1e30f; i1[t] = 0; }

    for (int it = 0; it < 16; it++) {
        const ushort_t* aptr = qbase + it*1024;
        short8 A1 = *(const short8*)aptr;
        short8 A2 = *(const short8*)(aptr + 32);
        f32x4 acc[4];
        #pragma unroll
        for (int t = 0; t < 4; t++) {
            acc[t] = (f32x4)0.f;
            acc[t] = __builtin_amdgcn_mfma_f32_16x16x32_bf16(A1, Bf[t][0], acc[t], 0, 0, 0);
            acc[t] = __builtin_amdgcn_mfma_f32_16x16x32_bf16(A1, Bf[t][1], acc[t], 0, 0, 0);
            acc[t] = __builtin_amdgcn_mfma_f32_16x16x32_bf16(A2, Bf[t][2], acc[t], 0, 0, 0);
        }
        int q0 = qh*2048 + wave*256 + it*16 + quad*4;
        #pragma unroll
        for (int r = 0; r < 4; r++) {
            int cand = q0 + r;
            #pragma unroll
            for (int t = 0; t < 4; t++) {
                float d = acc[t][r];
                float old1 = m1[t];
                bool gt = d > old1;
                m1[t] = gt ? d : old1;
                i1[t] = gt ? cand : i1[t];
                m2[t] = fmaxf(m2[t], fminf(d, old1));
            }
        }
    }

    #pragma unroll
    for (int t = 0; t < 4; t++) {
        int kl_ = t*16 + l15;
        int slot = wave*4 + quad;
        sM1[kl_*33 + slot] = m1[t];
        sI1[kl_*33 + slot] = i1[t];
        sM2[kl_*33 + slot] = m2[t];
    }
    __syncthreads();
    if (tid < 64) {
        float M1 = -1e30f; int I1 = 0x7fffffff;
        for (int s = 0; s < 32; s++) {
            float m = sM1[tid*33 + s]; int i = sI1[tid*33 + s];
            if (m > M1 || (m == M1 && i < I1)) { M1 = m; I1 = i; }
        }
        float M2 = -1e30f;
        for (int s = 0; s < 32; s++) {
            float m = sM1[tid*33 + s]; int i = sI1[tid*33 + s];
            float cnd = (i == I1) ? sM2[tid*33 + s] : m;
            M2 = fmaxf(M2, cnd);
        }
        int out = ((qh*4 + b) << 12) + kg*64 + tid;
        pm1[out] = M1; pi1[out] = I1; pm2[out] = M2;
    }
}

// ---------- Kernel 3: combine halves, flag low-margin rows ----------
__global__ __launch_bounds__(256) void fixup1_kernel(
    const float* __restrict__ pm1, const int* __restrict__ pi1,
    const float* __restrict__ pm2,
    float* __restrict__ maxv, int* __restrict__ idxv,
    int* __restrict__ gN, int* __restrict__ gList)
{
    int row = blockIdx.x*256 + threadIdx.x;
    int b = row >> 12, k = row & 4095;
    float m1a = pm1[(b<<12)+k];     int i1a = pi1[(b<<12)+k];     float m2a = pm2[(b<<12)+k];
    float m1b = pm1[((4+b)<<12)+k]; int i1b = pi1[((4+b)<<12)+k]; float m2b = pm2[((4+b)<<12)+k];
    float M1, ru; int I1;
    if (m1b > m1a) { M1 = m1b; I1 = i1b; ru = fmaxf(m1a, fmaxf(m2a, m2b)); }
    else           { M1 = m1a; I1 = i1a; ru = fmaxf(m1b, fmaxf(m2a, m2b)); }
    maxv[row] = M1; idxv[row] = I1;
    if (M1 - ru < MARGIN) {
        int p = atomicAdd(gN, 1);
        gList[p] = row;
    }
}

// ---------- Kernel 4: exact f32 rescan of flagged rows (parallel reduce) ----------
__global__ __launch_bounds__(256) void fixup2_kernel(
    const float* __restrict__ Qt, const float* __restrict__ Kt,
    const int* __restrict__ gN, const int* __restrict__ gList,
    float* __restrict__ maxv, int* __restrict__ idxv)
{
    __shared__ float sRm[256];
    __shared__ int   sRi[256];
    int n = *gN;
    int tid = threadIdx.x;
    for (int e = blockIdx.x; e < n; e += 64) {
        int r2 = gList[e];
        int b2 = r2 >> 12, k2 = r2 & 4095;
        const float4* Kp = (const float4*)(Kt + ((size_t)(b2*4096 + k2))*16);
        float4 ka = Kp[0], kbv = Kp[1], kc = Kp[2], kd = Kp[3];
        const float4* Qp = (const float4*)(Qt + ((size_t)b2*4096)*16);
        float m = -1e30f; int i = 0;
        #pragma unroll 4
        for (int j = 0; j < 16; j++) {
            int q = tid*16 + j;
            float4 qa = Qp[q*4+0], qb = Qp[q*4+1], qc = Qp[q*4+2], qd = Qp[q*4+3];
            float d = (dot4(ka,qa) + dot4(kbv,qb)) + (dot4(kc,qc) + dot4(kd,qd));
            if (d > m) { m = d; i = q; }
        }
        sRm[tid] = m; sRi[tid] = i;
        __syncthreads();
        #pragma unroll
        for (int s = 128; s > 0; s >>= 1) {
            if (tid < s) {
                float mo = sRm[tid+s]; int io = sRi[tid+s];
                if (mo > sRm[tid] || (mo == sRm[tid] && io < sRi[tid])) {
                    sRm[tid] = mo; sRi[tid] = io;
                }
            }
            __syncthreads();
        }
        if (tid == 0) { maxv[r2] = sRm[0]; idxv[r2] = sRi[0]; }
        __syncthreads();
    }
}

// ---------- Kernel 5: gather V columns -> xsel bf16 ----------
__global__ __launch_bounds__(256) void gather_kernel(
    const float* __restrict__ V, const int* __restrict__ idxv,
    ushort_t* __restrict__ xsel)
{
    int bid = blockIdx.x;
    int b = bid >> 6, pt = bid & 63;
    int tid = threadIdx.x;
    int pp = tid >> 2, cq = tid & 3;
    int p = pt*64 + pp;
    int ip = idxv[(b << 12) + p];
    const float* vb = V + ((size_t)b << 19) + ip;
    int site = ((p >> 6) + 1)*66 + (p & 63) + 1;
    ushort_t* dst = xsel + ((size_t)(b*4356 + site))*256 + 128 + cq*32;
    #pragma unroll
    for (int k = 0; k < 4; k++) {
        union { ushort_t s[8]; uint4 v; } pk;
        #pragma unroll
        for (int j = 0; j < 8; j++) {
            int c = cq*32 + k*8 + j;
            pk.s[j] = f2bf(vb[(size_t)c << 12]);
        }
        *(uint4*)(dst + k*8) = pk.v;
    }
}

// ---------- Kernel 6: 3x3 conv as bf16 MFMA shift-GEMM ----------
__global__ __launch_bounds__(256) void conv_kernel(
    const float* __restrict__ x, const ushort_t* __restrict__ xsel,
    const ushort_t* __restrict__ Wt, const float* __restrict__ bf,
    const float* __restrict__ maxv, float* __restrict__ out)
{
    __shared__ __align__(16) ushort_t sIn[336*32];
    __shared__ __align__(16) ushort_t sW[9*32*32];

    int bid = blockIdx.x;
    int og = bid & 3, tx = (bid >> 2) & 3, ty = (bid >> 4) & 3, b = bid >> 6;
    int tid = threadIdx.x;
    int wave = tid >> 6, lane = tid & 63;
    int l15 = lane & 15, quad = lane >> 4;

    const ushort_t* xsel_base = xsel + ((size_t)(b*4356 + (ty*16)*66 + tx*16))*256;
    const ushort_t* wt_base   = Wt + (size_t)og*8*9216;

    f32x4 acc[4][2];
    #pragma unroll
    for (int mi = 0; mi < 4; mi++)
        #pragma unroll
        for (int ni = 0; ni < 2; ni++) acc[mi][ni] = (f32x4)0.f;

    int l4q = lane >> 2, l4 = lane & 3;

    for (int cb = 0; cb < 8; cb++) {
        if (cb) __syncthreads();
        for (int r = wave; r < 21; r += 4) {
            int site = r*16 + l4q;
            int iy = site / 18, ix = site - iy*18;
            const ushort_t* g = xsel_base + (size_t)(iy*66 + ix)*256 + cb*32 + l4*8;
            gl2lds16(g, &sIn[r*512]);
        }
        for (int r = wave; r < 18; r += 4) {
            const ushort_t* g = wt_base + (size_t)cb*9216 + r*512 + lane*8;
            gl2lds16(g, &sW[r*512]);
        }
        __syncthreads();

        #pragma unroll
        for (int tap = 0; tap < 9; tap++) {
            const int dy = tap / 3, dx = tap % 3;
            short8 B0 = *(const short8*)&sW[(tap*32 +      l15)*32 + quad*8];
            short8 B1 = *(const short8*)&sW[(tap*32 + 16 + l15)*32 + quad*8];
            #pragma unroll
            for (int mi = 0; mi < 4; mi++) {
                int row = wave*4 + mi + dy;
                short8 A = *(const short8*)&sIn[(row*18 + l15 + dx)*32 + quad*8];
                acc[mi][0] = __builtin_amdgcn_mfma_f32_16x16x32_bf16(A, B0, acc[mi][0], 0, 0, 0);
                acc[mi][1] = __builtin_amdgcn_mfma_f32_16x16x32_bf16(A, B1, acc[mi][1], 0, 0, 0);
            }
        }
    }

    int y0 = ty*16, x0 = tx*16;
    const float* xb_ = x   + ((size_t)b << 19);
    float*       ob  = out + ((size_t)b << 19);
    const float* mxb = maxv + (b << 12);
    #pragma unroll
    for (int mi = 0; mi < 4; mi++) {
        int y = y0 + wave*4 + mi;
        int p = (y << 6) + x0 + quad*4;
        float4 mv = *(const float4*)&mxb[p];
        #pragma unroll
        for (int ni = 0; ni < 2; ni++) {
            int o = og*32 + ni*16 + l15;
            float bfo = bf[o];
            float4 xv = *(const float4*)&xb_[((size_t)o << 12) + p];
            float4 r;
            r.x = xv.x + mv.x * (acc[mi][ni][0] + bfo);
            r.y = xv.y + mv.y * (acc[mi][ni][1] + bfo);
            r.z = xv.z + mv.z * (acc[mi][ni][2] + bfo);
            r.w = xv.w + mv.w * (acc[mi][ni][3] + bfo);
            *(float4*)&ob[((size_t)o << 12) + p] = r;
        }
    }
}

extern "C" void kernel_launch(void* const* d_in, const int* in_sizes, int n_in,
                              void* d_out, int out_size, void* d_ws, size_t ws_size,
                              hipStream_t stream) {
    (void)in_sizes; (void)n_in; (void)out_size; (void)ws_size;
    const float* x  = (const float*)d_in[0];
    const float* xf = (const float*)d_in[1];
    const float* xb = (const float*)d_in[2];
    const float* Wq = (const float*)d_in[3];
    const float* bq = (const float*)d_in[4];
    const float* Wk = (const float*)d_in[5];
    const float* bk = (const float*)d_in[6];
    const float* Wv = (const float*)d_in[7];
    const float* bv = (const float*)d_in[8];
    const float* Wf = (const float*)d_in[9];
    const float* bf = (const float*)d_in[10];
    float* out = (float*)d_out;

    float* ws   = (float*)d_ws;
    float* Qt   = ws;                          // 262144 f
    float* Kt   = Qt + 262144;                 // 262144 f
    float* V    = Kt + 262144;                 // 2097152 f
    float* mx   = V  + 2097152;                // 16384 f
    int*   idxv = (int*)(mx + 16384);          // 16384 i
    float* pm1  = (float*)(idxv + 16384);      // 32768 f
    int*   pi1  = (int*)(pm1 + 32768);         // 32768 i
    float* pm2  = (float*)(pi1 + 32768);       // 32768 f
    int*   gN   = (int*)(pm2 + 32768);         // 4 i (pad)
    int*   gList= gN + 4;                      // 16384 i
    ushort_t* Qs   = (ushort_t*)(gList + 16384); // 1048576 sh
    ushort_t* KB   = Qs + 1048576;             // 1572864 sh
    ushort_t* xsel = KB + 1572864;             // 4460544 sh
    ushort_t* Wt   = xsel + 4460544;           // 294912 sh

    hipMemsetAsync(gN, 0, sizeof(int), stream);
    hipLaunchKernelGGL(prep_kernel,   dim3(690), dim3(256), 0, stream,
                       x, xf, xb, Wq, bq, Wk, bk, Wv, bv, Wf, Qt, Kt, V, Qs, KB, xsel, Wt);
    hipLaunchKernelGGL(att_kernel,    dim3(512), dim3(512), 0, stream, Qs, KB, pm1, pi1, pm2);
    hipLaunchKernelGGL(fixup1_kernel, dim3(64),  dim3(256), 0, stream, pm1, pi1, pm2, mx, idxv, gN, gList);
    hipLaunchKernelGGL(fixup2_kernel, dim3(64),  dim3(256), 0, stream, Qt, Kt, gN, gList, mx, idxv);
    hipLaunchKernelGGL(gather_kernel, dim3(256), dim3(256), 0, stream, V, idxv, xsel);
    hipLaunchKernelGGL(conv_kernel,   dim3(256), dim3(256), 0, stream, x, xsel, Wt, bf, mx, out);
}